// Round 4
// baseline (323.047 us; speedup 1.0000x reference)
//
#include <hip/hip_runtime.h>
#include <math.h>

#define DX 192
#define DY 192
#define DZ 128
#define DB 4
#define DXY (DX*DY)          // 36864
#define NTOT (DB*DZ*DXY)     // 18874368
#define XV (DX/4)            // 48 vec4 groups per row
#define NCOL (DB*DZ*XV)      // 24576 columns (b,z,xv4)
#define SEG 8                // y rows per thread
#define NSEG (DY/SEG)        // 24 segments per column

// ws layout (doubles): [0..12] sum(di*dt), [13..25] sum(dt*dt), [26] bce sum

__device__ inline float wred(float v) {
    #pragma unroll
    for (int o = 32; o > 0; o >>= 1) v += __shfl_down(v, o, 64);
    return v;
}

__device__ inline float4 ld4(const float* p) { return *(const float4*)p; }

// --- term macros -----------------------------------------------------------
#define TN(k, A1, A0, D1, D0) do { float di_=(A1)-(A0); float dt_=(D1)-(D0); \
    sk[k] += di_*dt_; rk[k] += dt_*dt_; } while(0)
#define TM(k, A1, A0, D1, D0) do { float di_=(A1)-(A0); float dt_=(D1)-(D0); \
    float dm_=fx3*dt_; sk[k] += di_*dm_; rk[k] += dt_*dm_; } while(0)
#define BCEACC(A0, D0) do { bces += (D0)*__logf(A0) + (1.0f-(D0))*__logf(1.0f-(A0)); } while(0)

// corners (z,y,x): a0=(0,0,0) a1=(0,0,1) a2=(0,1,0) a3=(0,1,1)
//                  a4=(1,0,0) a5=(1,0,1) a6=(1,1,0) a7=(1,1,1)
// offsets -> pairs: k0:(4,0) k1:(2,0) k2:(1,0) k3:(6,0) k4:(4,2) k5:(3,0)
//                   k6:(2,1) k7:(4,1) k8:(5,0) k9:(4,3) k10:(6,1) k11:(7,0) k12:(5,2)

#define ELEM_FULL(a0,a1,a2,a3,a4,a5,a6,a7, d0,d1,d2,d3,d4,d5,d6,d7) do { \
    TN(0,a4,a0,d4,d0); TN(1,a2,a0,d2,d0); TN(2,a1,a0,d1,d0); TN(3,a6,a0,d6,d0); \
    TN(4,a4,a2,d4,d2); TN(5,a3,a0,d3,d0); TN(6,a2,a1,d2,d1); TN(7,a4,a1,d4,d1); \
    TN(8,a5,a0,d5,d0); TN(9,a4,a3,d4,d3); TN(10,a6,a1,d6,d1); TN(11,a7,a0,d7,d0); \
    TN(12,a5,a2,d5,d2); BCEACC(a0,d0); } while(0)

#define ELEM_FX(a0,a1,a2,a3,a4,a5,a6,a7, d0,d1,d2,d3,d4,d5,d6,d7) do { \
    TN(0,a4,a0,d4,d0); TN(1,a2,a0,d2,d0); TM(2,a1,a0,d1,d0); TN(3,a6,a0,d6,d0); \
    TN(4,a4,a2,d4,d2); TM(5,a3,a0,d3,d0); TM(6,a2,a1,d2,d1); TM(7,a4,a1,d4,d1); \
    TM(8,a5,a0,d5,d0); TM(9,a4,a3,d4,d3); TM(10,a6,a1,d6,d1); TM(11,a7,a0,d7,d0); \
    TM(12,a5,a2,d5,d2); BCEACC(a0,d0); } while(0)

// y=191 peel (z<127): only dy==0 offsets survive: k0,k2,k7,k8
#define PEL_FULL(a0,a1,a4,a5, d0,d1,d4,d5) do { \
    TN(0,a4,a0,d4,d0); TN(2,a1,a0,d1,d0); TN(7,a4,a1,d4,d1); TN(8,a5,a0,d5,d0); \
    BCEACC(a0,d0); } while(0)
#define PEL_FX(a0,a1,a4,a5, d0,d1,d4,d5) do { \
    TN(0,a4,a0,d4,d0); TM(2,a1,a0,d1,d0); TM(7,a4,a1,d4,d1); TM(8,a5,a0,d5,d0); \
    BCEACC(a0,d0); } while(0)

// z=127 body: only dz==0 offsets survive: k1,k2,k5,k6
#define ZEL_FULL(a0,a1,a2,a3, d0,d1,d2,d3) do { \
    TN(1,a2,a0,d2,d0); TN(2,a1,a0,d1,d0); TN(5,a3,a0,d3,d0); TN(6,a2,a1,d2,d1); \
    BCEACC(a0,d0); } while(0)
#define ZEL_FX(a0,a1,a2,a3, d0,d1,d2,d3) do { \
    TN(1,a2,a0,d2,d0); TM(2,a1,a0,d1,d0); TM(5,a3,a0,d3,d0); TM(6,a2,a1,d2,d1); \
    BCEACC(a0,d0); } while(0)

// z=127, y=191 peel: only k2
#define ZPEL_FULL(a0,a1, d0,d1) do { TN(2,a1,a0,d1,d0); BCEACC(a0,d0); } while(0)
#define ZPEL_FX(a0,a1, d0,d1)   do { TM(2,a1,a0,d1,d0); BCEACC(a0,d0); } while(0)

// --- register-set machinery for the fully-unrolled pipeline ----------------
#define DECLSET(n) float4 i0_##n, i1_##n, t0_##n, t1_##n; \
                   float  ie_##n, iz_##n, te_##n, tz_##n;

#define LOADSET(n) do { \
    i0_##n = ld4(ip  + n*DX); i1_##n = ld4(ipz + n*DX); \
    t0_##n = ld4(tp  + n*DX); t1_##n = ld4(tpz + n*DX); \
    ie_##n = ipe[n*DX]; iz_##n = ipze[n*DX]; \
    te_##n = tpe[n*DX]; tz_##n = tpze[n*DX]; } while(0)

#define COMP(a,b) do { \
    ELEM_FULL(i0_##a.x,i0_##a.y, i0_##b.x,i0_##b.y, i1_##a.x,i1_##a.y, i1_##b.x,i1_##b.y, \
              t0_##a.x,t0_##a.y, t0_##b.x,t0_##b.y, t1_##a.x,t1_##a.y, t1_##b.x,t1_##b.y); \
    ELEM_FULL(i0_##a.y,i0_##a.z, i0_##b.y,i0_##b.z, i1_##a.y,i1_##a.z, i1_##b.y,i1_##b.z, \
              t0_##a.y,t0_##a.z, t0_##b.y,t0_##b.z, t1_##a.y,t1_##a.z, t1_##b.y,t1_##b.z); \
    ELEM_FULL(i0_##a.z,i0_##a.w, i0_##b.z,i0_##b.w, i1_##a.z,i1_##a.w, i1_##b.z,i1_##b.w, \
              t0_##a.z,t0_##a.w, t0_##b.z,t0_##b.w, t1_##a.z,t1_##a.w, t1_##b.z,t1_##b.w); \
    ELEM_FX  (i0_##a.w,ie_##a,  i0_##b.w,ie_##b,  i1_##a.w,iz_##a,  i1_##b.w,iz_##b, \
              t0_##a.w,te_##a,  t0_##b.w,te_##b,  t1_##a.w,tz_##a,  t1_##b.w,tz_##b); \
    } while(0)

#define PEEL(n) do { \
    PEL_FULL(i0_##n.x,i0_##n.y, i1_##n.x,i1_##n.y, t0_##n.x,t0_##n.y, t1_##n.x,t1_##n.y); \
    PEL_FULL(i0_##n.y,i0_##n.z, i1_##n.y,i1_##n.z, t0_##n.y,t0_##n.z, t1_##n.y,t1_##n.z); \
    PEL_FULL(i0_##n.z,i0_##n.w, i1_##n.z,i1_##n.w, t0_##n.z,t0_##n.w, t1_##n.z,t1_##n.w); \
    PEL_FX  (i0_##n.w,ie_##n,  i1_##n.w,iz_##n,  t0_##n.w,te_##n,  t1_##n.w,tz_##n); \
    } while(0)

__global__ __launch_bounds__(256, 3) void gc3d_main(const float* __restrict__ inp,
                                                    const float* __restrict__ tgt,
                                                    double* __restrict__ acc) {
    float sk[13] = {0,0,0,0,0,0,0,0,0,0,0,0,0};
    float rk[13] = {0,0,0,0,0,0,0,0,0,0,0,0,0};
    float bces = 0.f;

    int c   = blockIdx.x * 256 + threadIdx.x;   // [0, 24576)
    int s   = blockIdx.y;                       // [0, 24)
    int xv4 = c % XV;
    int zb  = c / XV;                           // b*DZ + z, [0, 512)
    int z   = zb & (DZ - 1);
    int y0  = s * SEG;
    bool xlast = (xv4 == XV - 1);
    int   xe   = xlast ? 3 : 4;
    float fx3  = xlast ? 0.f : 1.f;
    bool lastseg = (s == NSEG - 1);

    int base = (zb * DY + y0) * DX + xv4 * 4;
    const float* ip = inp + base;
    const float* tp = tgt + base;

    if (z != DZ - 1) {
        // ---------- z-interior: fully-unrolled straight-line pipeline ----------
        const float* ipz  = ip + DXY;
        const float* tpz  = tp + DXY;
        const float* ipe  = ip  + xe;
        const float* ipze = ipz + xe;
        const float* tpe  = tp  + xe;
        const float* tpze = tpz + xe;

        DECLSET(0) DECLSET(1) DECLSET(2) DECLSET(3) DECLSET(4)
        DECLSET(5) DECLSET(6) DECLSET(7) DECLSET(8)

        if (!lastseg) {
            // rows y0..y0+8 all exist (y0 <= 176 -> max row 184)
            LOADSET(0); LOADSET(1); LOADSET(2);
            LOADSET(3); COMP(0,1);
            LOADSET(4); COMP(1,2);
            LOADSET(5); COMP(2,3);
            LOADSET(6); COMP(3,4);
            LOADSET(7); COMP(4,5);
            LOADSET(8); COMP(5,6);
            COMP(6,7);
            COMP(7,8);
        } else {
            // s = 23: rows 184..191; 7 pair-steps + y=191 peel
            LOADSET(0); LOADSET(1); LOADSET(2);
            LOADSET(3); COMP(0,1);
            LOADSET(4); COMP(1,2);
            LOADSET(5); COMP(2,3);
            LOADSET(6); COMP(3,4);
            LOADSET(7); COMP(4,5);
            COMP(5,6);
            COMP(6,7);
            PEEL(7);
        }
    } else {
        // ---------- z = 127 path (0.8% of columns): small rolled pipeline ----------
        int nfull = SEG - (lastseg ? 1 : 0);
        float4 i0 = ld4(ip);
        float4 t0 = ld4(tp);
        float  i0e = ip[xe];
        float  t0e = tp[xe];
        float4 j0 = ld4(ip + DX);
        float4 u0 = ld4(tp + DX);
        float  j0e = ip[DX + xe];
        float  u0e = tp[DX + xe];

        #pragma unroll 2
        for (int it = 0; it < nfull - 1; ++it) {
            const float* ipk = ip + 2 * DX;
            const float* tpk = tp + 2 * DX;
            float4 k0 = ld4(ipk);
            float4 w0 = ld4(tpk);
            float  k0e = ipk[xe];
            float  w0e = tpk[xe];

            ZEL_FULL(i0.x,i0.y, j0.x,j0.y, t0.x,t0.y, u0.x,u0.y);
            ZEL_FULL(i0.y,i0.z, j0.y,j0.z, t0.y,t0.z, u0.y,u0.z);
            ZEL_FULL(i0.z,i0.w, j0.z,j0.w, t0.z,t0.w, u0.z,u0.w);
            ZEL_FX  (i0.w,i0e,  j0.w,j0e,  t0.w,t0e,  u0.w,u0e);

            i0 = j0; t0 = u0; i0e = j0e; t0e = u0e;
            j0 = k0; u0 = w0; j0e = k0e; u0e = w0e;
            ip += DX; tp += DX;
        }
        ZEL_FULL(i0.x,i0.y, j0.x,j0.y, t0.x,t0.y, u0.x,u0.y);
        ZEL_FULL(i0.y,i0.z, j0.y,j0.z, t0.y,t0.z, u0.y,u0.z);
        ZEL_FULL(i0.z,i0.w, j0.z,j0.w, t0.z,t0.w, u0.z,u0.w);
        ZEL_FX  (i0.w,i0e,  j0.w,j0e,  t0.w,t0e,  u0.w,u0e);

        if (lastseg) {
            ZPEL_FULL(j0.x,j0.y, u0.x,u0.y);
            ZPEL_FULL(j0.y,j0.z, u0.y,u0.z);
            ZPEL_FULL(j0.z,j0.w, u0.z,u0.w);
            ZPEL_FX  (j0.w,j0e,  u0.w,u0e);
        }
    }

    // block reduction: wave shuffle -> LDS -> 27 double atomics
    float vals[27];
    #pragma unroll
    for (int q = 0; q < 13; q++) { vals[q] = sk[q]; vals[13 + q] = rk[q]; }
    vals[26] = bces;
    #pragma unroll
    for (int q = 0; q < 27; q++) vals[q] = wred(vals[q]);

    __shared__ float red[4][27];
    int lane = threadIdx.x & 63;
    int wave = threadIdx.x >> 6;
    if (lane == 0) {
        #pragma unroll
        for (int q = 0; q < 27; q++) red[wave][q] = vals[q];
    }
    __syncthreads();
    if (threadIdx.x < 27) {
        float t = red[0][threadIdx.x] + red[1][threadIdx.x]
                + red[2][threadIdx.x] + red[3][threadIdx.x];
        atomicAdd(&acc[threadIdx.x], (double)t);
    }
}

__global__ void gc3d_final(const double* __restrict__ acc, float* __restrict__ out) {
    if (threadIdx.x == 0 && blockIdx.x == 0) {
        double s = 0.0;
        #pragma unroll
        for (int k = 0; k < 13; k++) s += acc[k] / (acc[13 + k] + 1e-5);
        double bce = -acc[26] / (double)NTOT;
        out[0] = (float)(bce + 1.0 - s / 13.0);
    }
}

extern "C" void kernel_launch(void* const* d_in, const int* in_sizes, int n_in,
                              void* d_out, int out_size, void* d_ws, size_t ws_size,
                              hipStream_t stream) {
    const float* inp = (const float*)d_in[0];
    const float* tgt = (const float*)d_in[1];
    double* acc = (double*)d_ws;

    hipMemsetAsync(d_ws, 0, 27 * sizeof(double), stream);
    dim3 grid(NCOL / 256, NSEG);
    gc3d_main<<<grid, 256, 0, stream>>>(inp, tgt, acc);
    gc3d_final<<<1, 64, 0, stream>>>(acc, (float*)d_out);
}